// Round 7
// baseline (724.450 us; speedup 1.0000x reference)
//
#include <hip/hip_runtime.h>

#define NB   256   // batch
#define NT   512   // time steps
#define NF   33    // features incl. flag channel
#define NFP  36    // padded/rotated x row (floats; 144 B)
#define BOND 64
#define NOUT 32

typedef _Float16 h2 __attribute__((ext_vector_type(2)));
typedef float    f4 __attribute__((ext_vector_type(4)));

__device__ __forceinline__ float fdot2(h2 p, h2 q, float c) {
    return __builtin_amdgcn_fdot2(p, q, c, false);   // v_dot2_f32_f16
}

__device__ __forceinline__ h2 pk2(float a, float b) {
    auto r = __builtin_amdgcn_cvt_pkrtz(a, b);       // v_cvt_pkrtz_f16_f32
    return __builtin_bit_cast(h2, r);
}

// One chain step. Lane owns (j, 4-wide i-slice). creg is only 64 VGPRs so the
// whole working set fits the 128-VGPR/4-waves-per-EU budget -> no spills.
__device__ __forceinline__ void do_step(int pa, int t,
                                        const h2 (&creg)[32][2],
                                        float& vj, float (*__restrict__ vbuf)[BOND],
                                        const float* __restrict__ xlds,
                                        int ic, int j, bool writer)
{
    // v pairs for this lane's i-slice: one 16B broadcast-ish read (2-way alias max)
    f4 va = *(const f4*)(&vbuf[pa][ic << 2]);

    // this step's x row (rotated layout: k<32 -> feature k+1, k=32 -> flag);
    // wave-uniform addresses -> LDS broadcast
    const float* xr = xlds + t * NFP;
    f4 xq[8];
    #pragma unroll
    for (int k = 0; k < 8; ++k) xq[k] = *(const f4*)(xr + 4 * k);
    float x0 = xr[32];

    h2 vp0 = pk2(va.x, va.y), vp1 = pk2(va.z, va.w);

    // partial for (j, i-slice): 4 independent accumulator chains over f
    float a0 = 0.f, a1 = 0.f, a2 = 0.f, a3 = 0.f;
    #pragma unroll
    for (int fq = 0; fq < 8; ++fq) {
        {
            const int ff = 4 * fq;
            float t0 = fdot2(vp0, creg[ff][0], 0.f);
            t0 = fdot2(vp1, creg[ff][1], t0);
            a0 = fmaf(xq[fq][0], t0, a0);
        }
        {
            const int ff = 4 * fq + 1;
            float t0 = fdot2(vp0, creg[ff][0], 0.f);
            t0 = fdot2(vp1, creg[ff][1], t0);
            a1 = fmaf(xq[fq][1], t0, a1);
        }
        {
            const int ff = 4 * fq + 2;
            float t0 = fdot2(vp0, creg[ff][0], 0.f);
            t0 = fdot2(vp1, creg[ff][1], t0);
            a2 = fmaf(xq[fq][2], t0, a2);
        }
        {
            const int ff = 4 * fq + 3;
            float t0 = fdot2(vp0, creg[ff][0], 0.f);
            t0 = fdot2(vp1, creg[ff][1], t0);
            a3 = fmaf(xq[fq][3], t0, a3);
        }
    }
    float acc = (a0 + a1) + (a2 + a3);

    // in-wave allreduce over the 16 i-slices (lanes that share j)
    acc += __shfl_xor(acc, 4, 64);
    acc += __shfl_xor(acc, 8, 64);
    acc += __shfl_xor(acc, 16, 64);
    acc += __shfl_xor(acc, 32, 64);

    float vnew = fmaf(x0, vj, acc);       // exact fp32 identity (flag) channel
    vj = vnew;
    if (writer) vbuf[pa ^ 1][j] = vnew;   // lanes with ic==0 publish 4 j's/wave

    __syncthreads();
}

// 1024 threads = 16 waves = 4 waves/SIMD at the 128-VGPR budget the allocator
// enforces regardless of launch bounds (R4-R6 evidence). Working set sized to
// FIT 128 instead of fighting for 256.
__global__ __launch_bounds__(1024, 4)
void umps_chain(const float* __restrict__ x,
                const float* __restrict__ core,
                const float* __restrict__ alpha,
                const float* __restrict__ oc,
                float* __restrict__ out)
{
    const int tid  = (int)threadIdx.x;
    const int lane = tid & 63;
    const int w    = tid >> 6;               // 0..15
    const int ic   = lane >> 2;              // i-slice: i in [4ic, 4ic+4)
    const int j    = (w << 2) + (lane & 3);  // this lane's output j
    const int b    = (int)blockIdx.x;

    __shared__ __align__(16) float xlds[NT * NFP];   // 73728 B
    __shared__ float vbuf[2][BOND];

    // ---- stage this batch's x into LDS (one-time, rotated layout) ----
    const float* xb = x + (size_t)b * (NT * NF);
    for (int idx = tid; idx < NT * NF; idx += 1024) {
        int t = idx / NF;
        int f = idx - t * NF;
        int k = (f == 0) ? 32 : (f - 1);
        xlds[t * NFP + k] = xb[idx];
    }

    // ---- core slice: creg[ff][p] = (C[4ic+2p, ff+1, j], C[4ic+2p+1, ff+1, j]) ----
    h2 creg[32][2];
    {
        const float* cb = core + (size_t)(4 * ic) * (NF * BOND) + BOND + j;
        #pragma unroll
        for (int p = 0; p < 2; ++p) {
            const float* c0 = cb + (size_t)(2 * p) * (NF * BOND);
            const float* c1 = cb + (size_t)(2 * p + 1) * (NF * BOND);
            #pragma unroll
            for (int ff = 0; ff < 32; ++ff)
                creg[ff][p] = pk2(c0[ff * BOND], c1[ff * BOND]);
        }
    }

    // ---- init carry ----
    float vj = alpha[j];
    if (tid < BOND) vbuf[0][tid] = alpha[tid];

    const bool writer = (ic == 0);

    __syncthreads();   // xlds + vbuf[0] ready

    #pragma unroll 1
    for (int t = 0; t < NT; t += 2) {
        do_step(0, t,     creg, vj, vbuf, xlds, ic, j, writer);
        do_step(1, t + 1, creg, vj, vbuf, xlds, ic, j, writer);
    }
    // final v is in vbuf[0][:], synced by the barrier inside the last step

    // ---- epilogue: out[b,:] = v @ output_core (64 x 32) ----
    if (tid < NOUT) {
        float s = 0.f;
        #pragma unroll
        for (int jj = 0; jj < BOND; ++jj)
            s = fmaf(vbuf[0][jj], oc[jj * NOUT + tid], s);
        out[b * NOUT + tid] = s;
    }
}

extern "C" void kernel_launch(void* const* d_in, const int* in_sizes, int n_in,
                              void* d_out, int out_size, void* d_ws, size_t ws_size,
                              hipStream_t stream) {
    const float* x     = (const float*)d_in[0];  // (256, 512, 33) f32
    const float* core  = (const float*)d_in[1];  // (64, 33, 64) f32
    const float* alpha = (const float*)d_in[2];  // (64,) f32
    const float* oc    = (const float*)d_in[3];  // (64, 32) f32
    float* out = (float*)d_out;                  // (256, 32) f32

    umps_chain<<<dim3(NB), dim3(1024), 0, stream>>>(x, core, alpha, oc, out);
}